// Round 17
// baseline (107.511 us; speedup 1.0000x reference)
//
#include <hip/hip_runtime.h>
#include <hip/hip_bf16.h>

#define B_ 2
#define T_ 2048
#define C_ 1024
#define H_ 16
#define D_ 64

typedef __attribute__((ext_vector_type(8))) short bf16x8;    // MFMA A/B operand (8 bf16)
typedef __attribute__((ext_vector_type(4))) float f32x4;     // 16x16 MFMA C/D
typedef __attribute__((ext_vector_type(16))) float f32x16;   // 32x32 MFMA C/D
typedef __attribute__((ext_vector_type(8))) unsigned short u16x8;
typedef __attribute__((ext_vector_type(2))) unsigned int u32x2;
typedef __attribute__((ext_vector_type(4))) unsigned int u32x4;

__device__ __forceinline__ unsigned short bf1(float a) {
    __bf16 x = (__bf16)a;
    return __builtin_bit_cast(unsigned short, x);
}
__device__ __forceinline__ unsigned int pk2(float a, float b) {
    return (unsigned int)bf1(a) | ((unsigned int)bf1(b) << 16);
}
__device__ __forceinline__ float bf2f(unsigned short u) {
    union { unsigned int u; float f; } v; v.u = (unsigned int)u << 16;
    return v.f;
}

__device__ __forceinline__ void gll16(const void* g, void* l) {
    __builtin_amdgcn_global_load_lds(
        (const __attribute__((address_space(1))) unsigned int*)g,
        (__attribute__((address_space(3))) unsigned int*)l, 16, 0, 0);
}

// ---------------------------------------------------------------------------
// Kernel 0: fused prep.  bid<1024: x f32->bf16 (xb). else: wq|wk|wv -> wb.
// ---------------------------------------------------------------------------
__global__ __launch_bounds__(256) void prep_all(
    const float* __restrict__ x, const float* __restrict__ wq,
    const float* __restrict__ wk, const float* __restrict__ wv,
    unsigned short* __restrict__ xb, unsigned short* __restrict__ wb)
{
    const int bid = blockIdx.x, tid = threadIdx.x;
    if (bid < 1024) {
        const size_t i = ((size_t)bid * 256 + tid) * 16;
        float4 f0 = *reinterpret_cast<const float4*>(x + i);
        float4 f1 = *reinterpret_cast<const float4*>(x + i + 4);
        float4 f2 = *reinterpret_cast<const float4*>(x + i + 8);
        float4 f3 = *reinterpret_cast<const float4*>(x + i + 12);
        u32x4 a = {pk2(f0.x, f0.y), pk2(f0.z, f0.w), pk2(f1.x, f1.y), pk2(f1.z, f1.w)};
        u32x4 b = {pk2(f2.x, f2.y), pk2(f2.z, f2.w), pk2(f3.x, f3.y), pk2(f3.z, f3.w)};
        *reinterpret_cast<u32x4*>(xb + i) = a;
        *reinterpret_cast<u32x4*>(xb + i + 8) = b;
    } else {
        const int rb = (bid - 1024) * 4;
        const float* src = (rb < 1024) ? wq + (size_t)rb * 1024
                         : (rb < 2048) ? wk + (size_t)(rb - 1024) * 1024
                                       : wv + (size_t)(rb - 2048) * 1024;
        const float sc = (rb < 1024) ? 0.125f * 1.4426950408889634f : 1.0f;
        const float4* s4 = (const float4*)src;
        u32x2* d = (u32x2*)(wb + (size_t)rb * 1024);
#pragma unroll
        for (int k = 0; k < 4; k++) {
            float4 v = s4[k * 256 + tid];
            u32x2 w;
            w[0] = pk2(v.x * sc, v.y * sc);
            w[1] = pk2(v.z * sc, v.w * sc);
            d[k * 256 + tid] = w;
        }
    }
}

// ---------------------------------------------------------------------------
// Kernel 1: qkv GEMM.  Z[4096,3072] = xb[4096,1024](bf16) * wb^T(bf16)
// m97 shape: BK=32, single-buffer 16KB LDS, both operands via gll16.
// Q,K written [b][h][t][d]; V written TRANSPOSED: vT[b][h][d][t].
// ---------------------------------------------------------------------------
__global__ __launch_bounds__(256) void qkv_gemm(
    const unsigned short* __restrict__ xb, const unsigned short* __restrict__ wb,
    unsigned short* __restrict__ qkv)
{
    __shared__ __align__(16) unsigned short As[128 * 32];
    __shared__ __align__(16) unsigned short Bs[128 * 32];
    const int tid = threadIdx.x;
    const int lane = tid & 63, wave = tid >> 6;
    const int g = lane >> 4, c16 = lane & 15;
    const int xcd = blockIdx.x & 7, idx = blockIdx.x >> 3;
    const int bm = (xcd << 2) + idx / 24, bn = idx % 24;
    const int jbase = bn << 7;
    const int which = jbase >> 10;

    const int srow = lane >> 2, sch = (lane & 3) << 3;
    const unsigned short* asrc = xb + ((size_t)(bm << 7) + wave * 32 + srow) * C_ + sch;
    const unsigned short* bsrc = wb + ((size_t)(bn << 7) + wave * 32 + srow) * C_ + sch;

    f32x4 acc[4][4];
#pragma unroll
    for (int i = 0; i < 4; i++)
#pragma unroll
        for (int j = 0; j < 4; j++) acc[i][j] = (f32x4){0.f, 0.f, 0.f, 0.f};

    const int wm = (wave >> 1) << 6, wn = (wave & 1) << 6;

    for (int t = 0; t < 32; ++t) {
        const int k0 = t << 5;
        __syncthreads();
        gll16(asrc + k0,           &As[(wave * 32) << 5]);
        gll16(asrc + k0 + 16 * C_, &As[(wave * 32 + 16) << 5]);
        gll16(bsrc + k0,           &Bs[(wave * 32) << 5]);
        gll16(bsrc + k0 + 16 * C_, &Bs[(wave * 32 + 16) << 5]);
        __syncthreads();

        bf16x8 af[4], bfv[4];
#pragma unroll
        for (int m = 0; m < 4; m++)
            af[m] = *reinterpret_cast<const bf16x8*>(&As[((wm + m * 16 + c16) << 5) + g * 8]);
#pragma unroll
        for (int n = 0; n < 4; n++)
            bfv[n] = *reinterpret_cast<const bf16x8*>(&Bs[((wn + n * 16 + c16) << 5) + g * 8]);
#pragma unroll
        for (int m = 0; m < 4; m++)
#pragma unroll
            for (int n = 0; n < 4; n++)
                acc[m][n] = __builtin_amdgcn_mfma_f32_16x16x32_bf16(af[m], bfv[n], acc[m][n], 0, 0, 0);
    }

    if (which < 2) {
#pragma unroll
        for (int m = 0; m < 4; m++) {
            const int grow = (bm << 7) + wm + m * 16 + (g << 2);
#pragma unroll
            for (int n = 0; n < 4; n++) {
                const int jj = (jbase + wn + n * 16 + c16) & 1023;
                const int h = jj >> 6, d = jj & 63;
#pragma unroll
                for (int r = 0; r < 4; r++) {
                    const int row = grow + r;
                    const int b = row >> 11, t = row & 2047;
                    const size_t off = ((size_t)((which * B_ + b) * H_ + h) * T_ + t) * 64 + d;
                    qkv[off] = bf1(acc[m][n][r]);
                }
            }
        }
    } else {
        // V transposed: vT[b][h][d][t]
#pragma unroll
        for (int m = 0; m < 4; m++) {
            const int grow = (bm << 7) + wm + m * 16 + (g << 2);
            const int b = grow >> 11, t = grow & 2047;
#pragma unroll
            for (int n = 0; n < 4; n++) {
                const int jj = (jbase + wn + n * 16 + c16) & 1023;
                const int h = jj >> 6, d = jj & 63;
                u32x2 w;
                w[0] = pk2(acc[m][n][0], acc[m][n][1]);
                w[1] = pk2(acc[m][n][2], acc[m][n][3]);
                const size_t off = ((size_t)((2 * B_ + b) * H_ + h) * 64 + d) * T_ + t;
                *reinterpret_cast<u32x2*>(&qkv[off]) = w;
            }
        }
    }
}

// ---------------------------------------------------------------------------
// Kernel 2: causal flash attention, STATIC-MAX softmax, 32x32x16 MFMA.
// QBLK=128: 4 waves x 32 q-rows. Halved LDS bytes/FLOP vs 16x16 (the R9-R16
// invariant was per-CU LDS throughput). l = lane-local sum (32x32 D-layout
// puts a full q-row in one lane). 2-way kv-split + combine as before.
// LDS 32KB: K[64x64] + V^T[64x64] + P[4][32x64], all XOR-chunk swizzled.
// ---------------------------------------------------------------------------
__global__ __launch_bounds__(256) void attn(
    const unsigned short* __restrict__ qkv,
    unsigned short* __restrict__ opA, unsigned short* __restrict__ opB,
    float* __restrict__ lbuf)
{
    __shared__ __align__(16) unsigned short Ks[64 * 64];
    __shared__ __align__(16) unsigned short Vt[64 * 64];
    __shared__ __align__(16) unsigned short Ps[4][32 * 64];
    const int tid = threadIdx.x, lane = tid & 63, w = tid >> 6;
    const int l31 = lane & 31, lh = lane >> 5;       // lane row / k-half
    const int qt = 15 - (blockIdx.x >> 6);           // longest first (16 q-tiles of 128)
    const int rem = blockIdx.x & 63;
    const int split = rem >> 5, bh = rem & 31;
    const int b = bh >> 4, h = bh & 15;
    const size_t headoff = (size_t)(b * H_ + h) * T_ * 64;
    const size_t QSZ = (size_t)B_ * H_ * T_ * 64;
    const unsigned short* qp = qkv + headoff;
    const unsigned short* kp = qkv + QSZ + headoff;
    const unsigned short* vTp = qkv + 2 * QSZ + headoff;   // [d][t]

    const int itlo = split ? (qt + 1) : 0;
    const int ithi = split ? (2 * qt + 2) : (qt + 1);

    const int qb = (qt << 7) + w * 32;          // wave q base (global)
    const int qg = qb + l31;                    // lane's q row (global)

    // Q B-frags: col q = l31, k-rows d = 16f + 8*lh + j
    bf16x8 qf[4];
#pragma unroll
    for (int f = 0; f < 4; f++)
        qf[f] = *reinterpret_cast<const bf16x8*>(qp + (size_t)qg * 64 + f * 16 + lh * 8);

    f32x16 oacc[2];
#pragma unroll
    for (int i = 0; i < 16; i++) { oacc[0][i] = 0.f; oacc[1][i] = 0.f; }
    float l_lane = 0.f;

    // ---- loop-invariant LDS base pointers (row = l31, chunk-XOR with l31&7) ----
    const int cx = l31 & 7;
    const unsigned short* kbase = Ks + (l31 << 6);
    const unsigned short* vbase = Vt + (l31 << 6);
    const unsigned short* prb = Ps[w] + (l31 << 6);
    unsigned short* pwb = Ps[w] + (l31 << 6);

    // ---- staging (pre-swizzled global source, linear LDS dest, rule 21) ----
    const int srow8 = lane >> 3;
    const int swc = ((lane & 7) ^ srow8) << 3;
    const unsigned short* ksrc = kp + (size_t)(w * 16 + srow8) * 64 + swc;
    const unsigned short* vsrc = vTp + (size_t)(w * 16 + srow8) * T_ + swc;

    for (int it = itlo; it < ithi; ++it) {
        const int s0 = it << 6;
        __syncthreads();                       // prev body done reading K/V
#pragma unroll
        for (int i = 0; i < 2; i++) {
            gll16(ksrc + (size_t)(s0 + i * 8) * 64, &Ks[(w * 16 + i * 8) << 6]);
            gll16(vsrc + s0 + (size_t)i * 8 * T_, &Vt[(w * 16 + i * 8) << 6]);
        }
        __syncthreads();                       // stage complete

        if (s0 > qb + 31) continue;            // wave fully masked (barriers done)

        // S^T quadrants [32kv x 32q], C-init = -16 (static-max bias)
        f32x16 sq[2];
#pragma unroll
        for (int i = 0; i < 16; i++) { sq[0][i] = -16.f; sq[1][i] = -16.f; }
        __builtin_amdgcn_s_setprio(1);
#pragma unroll
        for (int kf = 0; kf < 2; kf++) {
#pragma unroll
            for (int f = 0; f < 4; f++) {
                bf16x8 ka = *reinterpret_cast<const bf16x8*>(
                    kbase + (kf << 11) + ((((f << 1) + lh) ^ cx) << 3));
                sq[kf] = __builtin_amdgcn_mfma_f32_32x32x16_bf16(ka, qf[f], sq[kf], 0, 0, 0);
            }
        }
        __builtin_amdgcn_s_setprio(0);

        // causal mask (diagonal region only)
        if (s0 + 63 > qb) {
#pragma unroll
            for (int kf = 0; kf < 2; kf++)
#pragma unroll
                for (int r = 0; r < 16; r++) {
                    const int kv = s0 + (kf << 5) + (r & 3) + ((r >> 2) << 3) + (lh << 2);
                    if (kv > qg) sq[kf][r] = -1e30f;
                }
        }

        // static-max softmax: P = 2^sq ; l accumulated lane-locally (one q/lane)
#pragma unroll
        for (int kf = 0; kf < 2; kf++)
#pragma unroll
            for (int r = 0; r < 16; r++) {
                const float pv = __builtin_amdgcn_exp2f(sq[kf][r]);
                sq[kf][r] = pv;
                l_lane += pv;
            }

        // P -> Ps[w]: row q = l31, b64 per (kf, rr): kv = 32kf + 8rr + 4lh + 0..3
#pragma unroll
        for (int kf = 0; kf < 2; kf++)
#pragma unroll
            for (int rr = 0; rr < 4; rr++) {
                u32x2 wv;
                wv[0] = pk2(sq[kf][4 * rr], sq[kf][4 * rr + 1]);
                wv[1] = pk2(sq[kf][4 * rr + 2], sq[kf][4 * rr + 3]);
                *reinterpret_cast<u32x2*>(
                    pwb + ((((kf << 2) + rr) ^ cx) << 3) + (lh << 2)) = wv;
            }

        // O^T += V^T · P  (A = V^T[d][kv], B = P[kv][q])
        bf16x8 pB[4];
#pragma unroll
        for (int kf2 = 0; kf2 < 4; kf2++)
            pB[kf2] = *reinterpret_cast<const bf16x8*>(
                prb + ((((kf2 << 1) + lh) ^ cx) << 3));
        __builtin_amdgcn_s_setprio(1);
#pragma unroll
        for (int df = 0; df < 2; df++) {
#pragma unroll
            for (int kf2 = 0; kf2 < 4; kf2++) {
                bf16x8 va = *reinterpret_cast<const bf16x8*>(
                    vbase + (df << 11) + ((((kf2 << 1) + lh) ^ cx) << 3));
                oacc[df] = __builtin_amdgcn_mfma_f32_32x32x16_bf16(va, pB[kf2], oacc[df], 0, 0, 0);
            }
        }
        __builtin_amdgcn_s_setprio(0);
    }

    // epilogue: unnormalized partial O (bf16) + partial l (f32)
    unsigned short* op = split ? opB : opA;
    const size_t orow = ((size_t)b * T_ + qg) * 1024 + h * 64;
#pragma unroll
    for (int df = 0; df < 2; df++)
#pragma unroll
        for (int rr = 0; rr < 4; rr++) {
            const int d = (df << 5) + (rr << 3) + (lh << 2);
            u32x2 wv;
            wv[0] = pk2(oacc[df][4 * rr], oacc[df][4 * rr + 1]);
            wv[1] = pk2(oacc[df][4 * rr + 2], oacc[df][4 * rr + 3]);
            *reinterpret_cast<u32x2*>(&op[orow + d]) = wv;
        }
    l_lane += __shfl_xor(l_lane, 32, 64);
    if (lane < 32)
        lbuf[(size_t)split * (B_ * H_ * T_) + ((size_t)(b * H_ + h)) * T_ + qg] = l_lane;
}

// ---------------------------------------------------------------------------
// Kernel 2b (fused): bid<2048: y = (OA + OB) / (lA + lB); else wo-transpose.
// ---------------------------------------------------------------------------
__global__ __launch_bounds__(256) void combine_wo(
    const unsigned short* __restrict__ opA, const unsigned short* __restrict__ opB,
    const float* __restrict__ lbuf, unsigned short* __restrict__ y,
    const float* __restrict__ wo, unsigned short* __restrict__ wt)
{
    __shared__ unsigned short tile[64][72];
    const int bid = blockIdx.x, tid = threadIdx.x;
    if (bid < 2048) {
        const size_t i = ((size_t)bid * 256 + tid) * 8;
        const int hh = (int)((i >> 6) & 15);
        const int t = (int)((i >> 10) & 2047);
        const int bb = (int)(i >> 21);
        const size_t li = ((size_t)(bb * H_ + hh)) * T_ + t;
        const float inv = 1.0f / (lbuf[li] + lbuf[(size_t)B_ * H_ * T_ + li]);
        u16x8 a = *reinterpret_cast<const u16x8*>(opA + i);
        u16x8 c = *reinterpret_cast<const u16x8*>(opB + i);
        unsigned short o[8];
#pragma unroll
        for (int j = 0; j < 8; j++) o[j] = bf1((bf2f(a[j]) + bf2f(c[j])) * inv);
        *reinterpret_cast<u16x8*>(y + i) = *reinterpret_cast<u16x8*>(o);
    } else {
        const int wb2 = bid - 2048;
        const int tk = (wb2 & 15) << 6, tn = (wb2 >> 4) << 6;
        const int r = tid >> 2, cb = (tid & 3) << 4;
#pragma unroll
        for (int j = 0; j < 4; j++) {
            float4 v = *reinterpret_cast<const float4*>(
                wo + (size_t)(tk + r) * 1024 + tn + cb + j * 4);
            u32x2 w;
            w[0] = pk2(v.x, v.y);
            w[1] = pk2(v.z, v.w);
            *reinterpret_cast<u32x2*>(&tile[r][cb + j * 4]) = w;
        }
        __syncthreads();
        unsigned short buf[16];
#pragma unroll
        for (int j = 0; j < 16; j++) buf[j] = tile[cb + j][r];
        unsigned short* dst = wt + (size_t)(tn + r) * 1024 + tk + cb;
        *reinterpret_cast<u16x8*>(dst) = *reinterpret_cast<u16x8*>(buf);
        *reinterpret_cast<u16x8*>(dst + 8) = *reinterpret_cast<u16x8*>(buf + 8);
    }
}

// ---------------------------------------------------------------------------
// Kernel 3: out[4096,1024] = y(bf16) @ wt^T(bf16)
// m97 shape: 128x64 tiles (512 blocks), BK=32, single-buffer 12KB LDS.
// ---------------------------------------------------------------------------
__global__ __launch_bounds__(256) void out_proj(
    const unsigned short* __restrict__ y, const unsigned short* __restrict__ wt,
    float* __restrict__ out)
{
    __shared__ __align__(16) unsigned short As[128 * 32];
    __shared__ __align__(16) unsigned short Bs[64 * 32];
    const int tid = threadIdx.x;
    const int lane = tid & 63, wave = tid >> 6;
    const int g = lane >> 4, c16 = lane & 15;
    const int xcd = blockIdx.x & 7, idx = blockIdx.x >> 3;   // 512 = 8 * (4 bm * 16 bn)
    const int bm = (xcd << 2) + (idx >> 4), bn = idx & 15;
    const int wm = (wave >> 1) << 6, wn = (wave & 1) << 5;

    const int srow = lane >> 2, sch = (lane & 3) << 3;
    const unsigned short* ysrc = y + ((size_t)(bm << 7) + wave * 32 + srow) * 1024 + sch;
    const unsigned short* wsrc = wt + ((size_t)(bn << 6) + wave * 16 + srow) * 1024 + sch;

    f32x4 acc[4][2];
#pragma unroll
    for (int i = 0; i < 4; i++)
#pragma unroll
        for (int j = 0; j < 2; j++) acc[i][j] = (f32x4){0.f, 0.f, 0.f, 0.f};

    for (int t = 0; t < 32; ++t) {
        const int k0 = t << 5;
        __syncthreads();
        gll16(ysrc + k0,             &As[(wave * 32) << 5]);
        gll16(ysrc + k0 + 16 * 1024, &As[(wave * 32 + 16) << 5]);
        gll16(wsrc + k0,             &Bs[(wave * 16) << 5]);
        __syncthreads();

        bf16x8 af[4], bfr[2];
#pragma unroll
        for (int m = 0; m < 4; m++)
            af[m] = *reinterpret_cast<const bf16x8*>(&As[((wm + m * 16 + c16) << 5) + g * 8]);
#pragma unroll
        for (int n = 0; n < 2; n++)
            bfr[n] = *reinterpret_cast<const bf16x8*>(&Bs[((wn + n * 16 + c16) << 5) + g * 8]);
#pragma unroll
        for (int m = 0; m < 4; m++)
#pragma unroll
            for (int n = 0; n < 2; n++)
                acc[m][n] = __builtin_amdgcn_mfma_f32_16x16x32_bf16(af[m], bfr[n], acc[m][n], 0, 0, 0);
    }

#pragma unroll
    for (int m = 0; m < 4; m++) {
        const int grow = (bm << 7) + wm + m * 16 + (g << 2);
#pragma unroll
        for (int n = 0; n < 2; n++) {
            const int gcol = (bn << 6) + wn + n * 16 + c16;
#pragma unroll
            for (int r = 0; r < 4; r++)
                out[(size_t)(grow + r) * 1024 + gcol] = acc[m][n][r];
        }
    }
}

extern "C" void kernel_launch(void* const* d_in, const int* in_sizes, int n_in,
                              void* d_out, int out_size, void* d_ws, size_t ws_size,
                              hipStream_t stream) {
    const float* x  = (const float*)d_in[0];
    const float* wq = (const float*)d_in[1];
    const float* wk = (const float*)d_in[2];
    const float* wv = (const float*)d_in[3];
    const float* wo = (const float*)d_in[4];
    float* out = (float*)d_out;

    // ws (32 MB): [0,6) wb -> [0,8) opB/y ; [8,32) qkv -> [8,10) wt
    // d_out (16 MB): [0,8) xb -> opA ; [8,8.5) lbuf ; out_proj overwrites all.
    unsigned short* wb   = (unsigned short*)d_ws;
    unsigned short* opB  = (unsigned short*)d_ws;
    unsigned short* y    = opB;
    unsigned short* qkv  = (unsigned short*)d_ws + (size_t)4 * 1024 * 1024;
    unsigned short* wt   = qkv;
    unsigned short* xb   = (unsigned short*)d_out;
    unsigned short* opA  = (unsigned short*)d_out;
    float* lbuf = (float*)((char*)d_out + (size_t)8 * 1024 * 1024);

    prep_all<<<dim3(1792), 256, 0, stream>>>(x, wq, wk, wv, xb, wb);
    qkv_gemm<<<dim3(768), 256, 0, stream>>>(xb, wb, qkv);
    attn<<<dim3(1024), 256, 0, stream>>>(qkv, opA, opB, lbuf);
    combine_wo<<<dim3(2048 + 256), 256, 0, stream>>>(opA, opB, lbuf, y, wo, wt);
    out_proj<<<dim3(512), 256, 0, stream>>>(y, wt, out);
}